// Round 23
// baseline (186.202 us; speedup 1.0000x reference)
//
#include <hip/hip_runtime.h>
#include <hip/hip_fp8.h>

#define BB 4
#define CC 256
#define HH 128
#define WW 128
#define NN (HH*WW)
#define EPSF 1e-10f

// padded NHWC x: [b][row 0..129][col 0..129][ic 0..255], data at row/col 1..128
#define XR 130
#define XPB ((size_t)XR*XR*CC)

typedef __bf16 bf16x8 __attribute__((ext_vector_type(8)));
typedef float  f32x4  __attribute__((ext_vector_type(4)));
typedef float  f32x16 __attribute__((ext_vector_type(16)));
typedef unsigned char uchar;

__device__ __forceinline__ float delu_f(float v) {
    // x>0: 10x+1 ; x<=0: exp(10x)
    return v > 0.0f ? fmaf(10.0f, v, 1.0f) : __expf(10.0f * v);
}

__device__ __forceinline__ uchar fp8b(float f) { return __hip_fp8_e4m3(f).__x; }
__device__ __forceinline__ float fp8f(uchar v) { __hip_fp8_e4m3 t; t.__x = v; return (float)t; }

// async global->LDS, 16B per lane: LDS dest = base + lane*16 (linear), global src per-lane
__device__ __forceinline__ void gl_lds16(const void* g, void* l) {
    __builtin_amdgcn_global_load_lds(
        (const __attribute__((address_space(1))) void*)g,
        (__attribute__((address_space(3))) void*)l, 16, 0, 0);
}

// ---------------- prep (weight packs) + halo (xpad border zero), merged launch
// bf16 1x1: wpk32[gks][ocf32][lane][e(bf16)]; fp8 conv: wcv8[t][gks][ocf32][lane][e], w*16, wd1 folded t=4
__global__ __launch_bounds__(256) void k_prep_halo(const float* __restrict__ wq,
    const float* __restrict__ wk, const float* __restrict__ wv,
    const float* __restrict__ wd1, const float* __restrict__ wd3,
    __bf16* __restrict__ wqb, __bf16* __restrict__ wkb, __bf16* __restrict__ wvb,
    uchar* __restrict__ wcv8,
    __bf16* __restrict__ xpad, uchar* __restrict__ xpad8)
{
    const int bi = blockIdx.x;
    if (bi >= CC*CC/256) {
        // halo part: 64 blocks (16 per batch)
        const int sub = bi - CC*CC/256;
        const int b = sub >> 4;
        for (int t = (sub & 15)*256 + threadIdx.x; t < 516*32; t += 256*16) {
            const int icg = t & 31;
            const int p   = t >> 5;
            int xrow, xcol;
            if (p < 260)      { xrow = (p < 130) ? 0 : 129; xcol = p % 130; }
            else              { int q = p - 260; xrow = 1 + (q >> 1); xcol = (q & 1) ? 129 : 0; }
            const size_t off = (size_t)b*XPB + ((size_t)xrow*XR + xcol)*CC + icg*8;
            *(bf16x8*)&xpad[off] = (bf16x8){};
            *(unsigned long long*)&xpad8[off] = 0ull;
        }
        return;
    }
    int idx = bi * 256 + threadIdx.x;   // oc*256+ic
    const int oc = idx >> 8, ic = idx & 255;
    const int ocf32 = oc >> 5;
    const int gks = ic >> 4, khi = (ic >> 3) & 1;
    const int lane32 = khi*32 + (oc & 31);
    const int e = ic & 7;
    const size_t off32 = ((size_t)(gks*8 + ocf32)*64 + lane32)*8 + e;
    wqb[off32] = (__bf16)wq[idx];
    wkb[off32] = (__bf16)wk[idx];
    wvb[off32] = (__bf16)wv[idx];
    float w9[9];
    #pragma unroll
    for (int k=0;k<9;k++) w9[k] = wd3[(size_t)idx*9 + k];
    w9[4] += wd1[idx];
    #pragma unroll
    for (int t=0;t<9;t++) wcv8[(size_t)t*CC*CC + off32] = fp8b(w9[t] * 16.0f);
}

// ---------------- stage 128n x 256ic bf16 tile (one image row): xs[kq 0..31][n 0..131(132)][ic8]
__device__ __forceinline__ void stage_row128(const __bf16* __restrict__ xrb,
                                             __bf16* __restrict__ xs,
                                             int wid, int lane)
{
    #pragma unroll
    for (int j = 0; j < 16; ++j) {
        const int it = wid + 4*j;
        const int kq = it >> 1, ch = it & 1;
        gl_lds16(xrb + (size_t)(ch*64 + lane)*CC + kq*8, &xs[(size_t)(kq*132 + ch*64)*8]);
    }
}

// ---------------- 64oc x 128n x 256ic GEMM via 32x32x16 bf16; A packed (L2), B LDS
__device__ __forceinline__ void mfma_gemm32(const __bf16* __restrict__ wb,
                                            const __bf16* __restrict__ xs,
                                            int wid, int lane, int l31, int lhi,
                                            f32x16 acc[2][4])
{
    #pragma unroll
    for (int kb=0; kb<8; kb++) {
        bf16x8 af[4];
        #pragma unroll
        for (int f=0; f<2; f++)
            #pragma unroll
            for (int kk=0; kk<2; kk++)
                af[f*2+kk] = *(const bf16x8*)&wb[((size_t)((kb*2+kk)*8 + wid*2 + f)*64 + lane)*8];
        #pragma unroll
        for (int kk=0; kk<2; kk++)
            #pragma unroll
            for (int nf=0; nf<4; nf++) {
                bf16x8 br = *(const bf16x8*)&xs[(size_t)((kb*4 + kk*2 + lhi)*132 + nf*32 + l31)*8];
                #pragma unroll
                for (int f=0; f<2; f++)
                    acc[f][nf] = __builtin_amdgcn_mfma_f32_32x32x16_bf16(af[f*2+kk], br, acc[f][nf], 0, 0, 0);
            }
    }
}

// ---------------- FUSED: x(fp32,NCHW) -> LDS transpose -> xpad bf16+fp8 writes -> Q/K GEMMs
__global__ __launch_bounds__(256) void k_qk_mfma(const float* __restrict__ x,
    const __bf16* __restrict__ wqb, const float* __restrict__ bq,
    const __bf16* __restrict__ wkb, const float* __restrict__ bk,
    uchar* __restrict__ kp8, float* __restrict__ Qs,
    __bf16* __restrict__ xpad, uchar* __restrict__ xpad8)
{
    __shared__ __bf16 xs[32*132*8];
    __shared__ float Qpart[4][128];
    const int h  = blockIdx.x;
    const int n0 = h * 128;
    const int b  = blockIdx.y;
    const int tid = threadIdx.x;
    const int wid = tid >> 6, lane = tid & 63;
    const int l31 = lane & 31, lhi = lane >> 5;
    const int oc_base = wid*64;

    // phase 1: transpose-stage x fp32 -> xs bf16
    const float* xb = x + (size_t)b*CC*NN + (size_t)h*WW;
    {
        const int ic7 = tid & 7;
        const int col = ((tid >> 3) & 31) * 4;
        #pragma unroll
        for (int i = 0; i < 32; ++i) {
            const int ic = i*8 + ic7;
            float4 v = *(const float4*)&xb[(size_t)ic*NN + col];
            const int b0 = (i*132 + col)*8 + ic7;
            xs[b0]      = (__bf16)v.x;
            xs[b0 + 8]  = (__bf16)v.y;
            xs[b0 + 16] = (__bf16)v.z;
            xs[b0 + 24] = (__bf16)v.w;
        }
    }
    __syncthreads();

    // phase 1b: write global xpad bf16 + fp8 (512B-contiguous stores per col)
    {
        __bf16* xpb  = xpad  + (size_t)b*XPB + ((size_t)(h+1)*XR + 1)*CC;
        uchar*  xpb8 = xpad8 + (size_t)b*XPB + ((size_t)(h+1)*XR + 1)*CC;
        #pragma unroll
        for (int it = 0; it < 16; ++it) {
            const int o   = it*256 + tid;   // 4096 = 128 col x 32 kq
            const int col = o >> 5, kq = o & 31;
            bf16x8 v = *(const bf16x8*)&xs[(size_t)(kq*132 + col)*8];
            unsigned long long pk = 0;
            #pragma unroll
            for (int j = 0; j < 8; ++j)
                pk |= ((unsigned long long)fp8b((float)v[j])) << (8*j);
            *(bf16x8*)&xpb[(size_t)col*CC + kq*8] = v;
            *(unsigned long long*)&xpb8[(size_t)col*CC + kq*8] = pk;
        }
    }

    // --- Q phase ---
    f32x16 acc[2][4] = {};
    mfma_gemm32(wqb, xs, wid, lane, l31, lhi, acc);
    #pragma unroll
    for (int nf=0; nf<4; nf++) {
        float s = 0.0f;
        #pragma unroll
        for (int f=0; f<2; f++)
            #pragma unroll
            for (int reg=0; reg<16; reg++) {
                const int oc = oc_base + f*32 + (reg&3) + 8*(reg>>2) + 4*lhi;
                s += delu_f(acc[f][nf][reg] + bq[oc]);
            }
        s += __shfl_xor(s, 32);
        if (lhi == 0) Qpart[wid][nf*32 + l31] = s;
    }
    __syncthreads();
    if (tid < 128)
        Qs[(size_t)b*NN + n0 + tid] = Qpart[0][tid] + Qpart[1][tid] + Qpart[2][tid] + Qpart[3][tid];

    // --- K phase ---
    #pragma unroll
    for (int f=0; f<2; f++)
        #pragma unroll
        for (int nf=0; nf<4; nf++)
            acc[f][nf] = (f32x16){};
    mfma_gemm32(wkb, xs, wid, lane, l31, lhi, acc);
    #pragma unroll
    for (int f=0; f<2; f++) {
        #pragma unroll
        for (int reg=0; reg<16; reg++) {
            const int oc = oc_base + f*32 + (reg&3) + 8*(reg>>2) + 4*lhi;
            const float bias = bk[oc];
            uchar* kr = kp8 + ((size_t)b*CC + oc)*NN + n0;
            #pragma unroll
            for (int nf=0; nf<4; nf++)
                kr[nf*32 + l31] = fp8b(delu_f(acc[f][nf][reg] + bias));
        }
    }
}

// ---------------- MERGED conv + esum dispatch, interleaved 1:2 (bi%3==0 -> conv, else esum).
// conv: 3x3(+1x1) via 32x32x16 fp8 MFMA (R19-proven, depth-2 af), writes convout fp8.
// esum: Es[b,c] = sum_n Qs[b,n]*k'[b,c,n] -- independent of conv, hides under its stalls.
__global__ __launch_bounds__(256,2) void k_conv_esum(const uchar* __restrict__ xpad8,
    const uchar* __restrict__ wcv8, const float* __restrict__ bd1,
    const float* __restrict__ bd3, uchar* __restrict__ convout8,
    const uchar* __restrict__ kp8, const float* __restrict__ Qs,
    float* __restrict__ Es)
{
    __shared__ uchar xs8[2][6*132*16];
    const int bi = blockIdx.x;
    const int tid = threadIdx.x;

    if (bi % 3 != 0) {
        // ---- esum block ----
        __shared__ float red[4];
        const int ei = (bi/3)*2 + (bi%3) - 1;   // 0..1023
        const int c = ei & (CC-1), b = ei >> 8;
        const uchar* kr = kp8 + ((size_t)b*CC + c)*NN;
        const float4* qr = (const float4*)(Qs + (size_t)b*NN);
        float s = 0.0f;
        for (int i = tid; i < NN/8; i += 256) {
            unsigned long long kkb = *(const unsigned long long*)&kr[(size_t)i*8];
            float4 q0 = qr[2*i], q1 = qr[2*i+1];
            const float qv[8] = {q0.x,q0.y,q0.z,q0.w,q1.x,q1.y,q1.z,q1.w};
            #pragma unroll
            for (int j=0;j<8;j++)
                s = fmaf(fp8f((uchar)(kkb >> (8*j))), qv[j], s);
        }
        #pragma unroll
        for (int m=1; m<64; m<<=1) s += __shfl_xor(s, m, 64);
        if ((tid & 63) == 0) red[tid >> 6] = s;
        __syncthreads();
        if (tid == 0) Es[b*CC + c] = red[0] + red[1] + red[2] + red[3];
        return;
    }

    // ---- conv block ----
    // bijective XCD swizzle over the 512 conv sub-blocks
    const int orig = bi / 3;
    const int wg   = (orig & 7)*64 + (orig >> 3);
    const int b    = wg >> 7;
    const int h    = wg & 127;
    const int wid = tid >> 6, lane = tid & 63;
    const int l31 = lane & 31, lhi = lane >> 5;
    const int oc_base = wid*64;
    const uchar* xpb8 = xpad8 + (size_t)b*XPB;

    f32x16 acc[2][4] = {};

    #define STAGE_CV8(bufsel, icb) do {                                         \
        const int ic0_ = (icb)*32;                                              \
        _Pragma("unroll")                                                       \
        for (int j = 0; j < 5; ++j) {                                           \
            const int w_ = wid + 4*j;                                           \
            if (w_ < 18) {                                                      \
                const int pair_ = w_ / 3, chunk_ = w_ % 3;                      \
                const int r_ = pair_ >> 1, g16_ = pair_ & 1;                    \
                const int col0_ = chunk_ * 64;                                  \
                if (col0_ + lane < XR)                                          \
                    gl_lds16(xpb8 + ((size_t)(h + r_)*XR + col0_ + lane)*CC + ic0_ + g16_*16, \
                             &xs8[bufsel][(size_t)(pair_*132 + col0_)*16]);     \
            }                                                                   \
        }                                                                       \
    } while (0)

    #define AF8_LOAD(dst, t, icb)                                               \
        _Pragma("unroll")                                                       \
        for (int f=0; f<2; f++)                                                 \
            _Pragma("unroll")                                                   \
            for (int kk=0; kk<2; kk++)                                          \
                dst[f*2+kk] = *(const long*)&wcv8[(size_t)(t)*CC*CC +           \
                    ((size_t)((((icb)*2 + kk)*8 + wid*2 + f))*64 + lane)*8];

    STAGE_CV8(0, 0);
    __syncthreads();

    #pragma unroll 1
    for (int icb = 0; icb < 8; ++icb) {
        long af8[2][4];
        AF8_LOAD(af8[0], 0, icb);
        if (icb < 7) STAGE_CV8((icb+1)&1, icb+1);
        #pragma unroll
        for (int t=0; t<9; ++t) {
            const int cur = t & 1, nxt = cur ^ 1;
            const int ky = t/3, kx = t%3;
            if (t < 8) { AF8_LOAD(af8[nxt], t+1, icb); }
            __builtin_amdgcn_s_setprio(1);
            #pragma unroll
            for (int kk=0; kk<2; kk++) {
                #pragma unroll
                for (int nf=0; nf<4; nf++) {
                    long br = *(const long*)&xs8[icb & 1][
                        (size_t)((ky*2 + kk)*132 + nf*32 + l31 + kx)*16 + lhi*8];
                    #pragma unroll
                    for (int f=0; f<2; f++)
                        acc[f][nf] = __builtin_amdgcn_mfma_f32_32x32x16_fp8_fp8(
                            af8[cur][f*2+kk], br, acc[f][nf], 0, 0, 0);
                }
            }
            __builtin_amdgcn_s_setprio(0);
        }
        __syncthreads();
    }
    #undef STAGE_CV8
    #undef AF8_LOAD

    #pragma unroll
    for (int f=0; f<2; f++) {
        #pragma unroll
        for (int reg=0; reg<16; reg++) {
            const int row = (reg & 3) + 8*(reg >> 2) + 4*lhi;
            const int oc = oc_base + f*32 + row;
            const float bias = bd1[oc] + bd3[oc];
            uchar* orow = convout8 + ((size_t)b*CC + oc)*NN + (size_t)h*WW;
            #pragma unroll
            for (int nf=0; nf<4; nf++) {
                const int w = nf*32 + l31;
                orow[w] = fp8b(acc[f][nf][reg]*0.0625f + bias);
            }
        }
    }
}

// ---------------- v projection via 32x32 MFMA + in-block denom + FINAL fused epilogue:
// out = x(from LDS xs, bf16) + g*(Es*k'*rn*(v+bv) + convout)
__global__ __launch_bounds__(256) void k_vattn_mfma(
    const __bf16* __restrict__ xpad,
    const __bf16* __restrict__ wvb, const float* __restrict__ bv,
    const uchar* __restrict__ kp8, const float* __restrict__ Es,
    const uchar* __restrict__ convout8,
    const float* __restrict__ gamma, float* __restrict__ out)
{
    __shared__ __bf16 xs[32*132*8];
    __shared__ float Dpart[4][128];
    __shared__ float rn_sh[128];
    const int h  = blockIdx.x;
    const int n0 = h * 128;
    const int b  = blockIdx.y;
    const int tid = threadIdx.x;
    const int wid = tid >> 6, lane = tid & 63;
    const int l31 = lane & 31, lhi = lane >> 5;
    const int oc_base = wid*64;
    const __bf16* xrb = xpad + (size_t)b*XPB + ((size_t)(h+1)*XR + 1)*CC;

    stage_row128(xrb, xs, wid, lane);
    __syncthreads();

    f32x16 acc[2][4] = {};
    mfma_gemm32(wvb, xs, wid, lane, l31, lhi, acc);

    // denom partials: sum over this wave's 64 oc of Es[oc]*k'[oc][n]
    float dpart[4] = {0.f,0.f,0.f,0.f};
    #pragma unroll
    for (int f=0; f<2; f++) {
        #pragma unroll
        for (int reg=0; reg<16; reg++) {
            const int oc = oc_base + f*32 + (reg&3) + 8*(reg>>2) + 4*lhi;
            const float e = Es[b*CC + oc];
            const uchar* kr = kp8 + ((size_t)b*CC + oc)*NN + n0;
            #pragma unroll
            for (int nf=0; nf<4; nf++)
                dpart[nf] = fmaf(e, fp8f(kr[nf*32 + l31]), dpart[nf]);
        }
    }
    #pragma unroll
    for (int nf=0; nf<4; nf++) {
        dpart[nf] += __shfl_xor(dpart[nf], 32);
        if (lhi == 0) Dpart[wid][nf*32 + l31] = dpart[nf];
    }
    __syncthreads();
    if (tid < 128)
        rn_sh[tid] = 1.0f / (Dpart[0][tid] + Dpart[1][tid] + Dpart[2][tid] + Dpart[3][tid] + EPSF);
    __syncthreads();

    const float g = gamma[0];
    #pragma unroll
    for (int f=0; f<2; f++) {
        #pragma unroll
        for (int reg=0; reg<16; reg++) {
            const int oc = oc_base + f*32 + (reg&3) + 8*(reg>>2) + 4*lhi;
            const float eg = Es[b*CC + oc] * g;
            const float bias = bv[oc];
            const uchar* kr = kp8 + ((size_t)b*CC + oc)*NN + n0;
            const uchar* cr = convout8 + ((size_t)b*CC + oc)*NN + n0;
            const __bf16* xr = &xs[(size_t)((oc >> 3)*132)*8 + (oc & 7)];
            float* orow = out + ((size_t)b*CC + oc)*NN + n0;
            #pragma unroll
            for (int nf=0; nf<4; nf++) {
                const int w = nf*32 + l31;
                const float attn = eg*fp8f(kr[w])*rn_sh[w]*(acc[f][nf][reg] + bias);
                const float xv = (float)xr[(size_t)w*8];
                orow[w] = xv + attn + g*fp8f(cr[w]);
            }
        }
    }
}

extern "C" void kernel_launch(void* const* d_in, const int* in_sizes, int n_in,
                              void* d_out, int out_size, void* d_ws, size_t ws_size,
                              hipStream_t stream)
{
    const float* x     = (const float*)d_in[0];
    const float* wq    = (const float*)d_in[1];
    const float* bq    = (const float*)d_in[2];
    const float* wk    = (const float*)d_in[3];
    const float* bk    = (const float*)d_in[4];
    const float* wv    = (const float*)d_in[5];
    const float* bv    = (const float*)d_in[6];
    const float* wd1   = (const float*)d_in[7];
    const float* bd1   = (const float*)d_in[8];
    const float* wd3   = (const float*)d_in[9];
    const float* bd3   = (const float*)d_in[10];
    const float* gamma = (const float*)d_in[11];
    float* out = (float*)d_out;

    uchar*  kp8    = (uchar*)d_ws;                      // B*C*N bytes (16.8 MB)
    uchar*  cvout8 = kp8 + (size_t)BB*CC*NN;            // B*C*N bytes (16.8 MB)
    float*  Qs     = (float*)(cvout8 + (size_t)BB*CC*NN); // B*N
    float*  Es     = Qs + (size_t)BB*NN;                // B*C
    uchar*  wcv8   = (uchar*)(Es + (size_t)BB*CC);      // [9][256][256] fp8 (0.6 MB)
    __bf16* wqb    = (__bf16*)(wcv8 + (size_t)9*CC*CC); // [256][256] bf16, 32x32-pack
    __bf16* wkb    = wqb + (size_t)CC*CC;
    __bf16* wvb    = wkb + (size_t)CC*CC;
    __bf16* xpad   = wvb + (size_t)CC*CC;               // [4][130][130][256] bf16 (34.6 MB)
    uchar*  xpad8  = (uchar*)(xpad + (size_t)BB*XPB);   // [4][130][130][256] fp8 (17.3 MB)

    k_prep_halo <<<dim3(CC*CC/256 + 16*BB), 256, 0, stream>>>(
                    wq, wk, wv, wd1, wd3, wqb, wkb, wvb, wcv8, xpad, xpad8);
    k_qk_mfma   <<<dim3(HH, BB), 256, 0, stream>>>(x, wqb, bq, wkb, bk, kp8, Qs, xpad, xpad8);
    k_conv_esum <<<dim3(3*HH*BB), 256, 0, stream>>>(xpad8, wcv8, bd1, bd3, cvout8,
                                                    kp8, Qs, Es);
    k_vattn_mfma<<<dim3(HH, BB), 256, 0, stream>>>(xpad, wvb, bv, kp8, Es, cvout8, gamma, out);
}

// Round 24
// 161.955 us; speedup vs baseline: 1.1497x; 1.1497x over previous
//
#include <hip/hip_runtime.h>
#include <hip/hip_fp8.h>

#define BB 4
#define CC 256
#define HH 128
#define WW 128
#define NN (HH*WW)
#define EPSF 1e-10f

// padded NHWC x: [b][row 0..129][col 0..129][ic 0..255], data at row/col 1..128
#define XR 130
#define XPB ((size_t)XR*XR*CC)

typedef __bf16 bf16x8 __attribute__((ext_vector_type(8)));
typedef float  f32x4  __attribute__((ext_vector_type(4)));
typedef float  f32x16 __attribute__((ext_vector_type(16)));
typedef unsigned char uchar;

__device__ __forceinline__ float delu_f(float v) {
    // x>0: 10x+1 ; x<=0: exp(10x)
    return v > 0.0f ? fmaf(10.0f, v, 1.0f) : __expf(10.0f * v);
}

__device__ __forceinline__ uchar fp8b(float f) { return __hip_fp8_e4m3(f).__x; }
__device__ __forceinline__ float fp8f(uchar v) { __hip_fp8_e4m3 t; t.__x = v; return (float)t; }

// async global->LDS, 16B per lane: LDS dest = base + lane*16 (linear), global src per-lane
__device__ __forceinline__ void gl_lds16(const void* g, void* l) {
    __builtin_amdgcn_global_load_lds(
        (const __attribute__((address_space(1))) void*)g,
        (__attribute__((address_space(3))) void*)l, 16, 0, 0);
}

// ---------------- prep (weight packs) + halo (xpad border zero), merged launch
// bf16 1x1: wpk32[gks][ocf32][lane][e(bf16)]; fp8 conv: wcv8[t][gks][ocf32][lane][e], w*16, wd1 folded t=4
__global__ __launch_bounds__(256) void k_prep_halo(const float* __restrict__ wq,
    const float* __restrict__ wk, const float* __restrict__ wv,
    const float* __restrict__ wd1, const float* __restrict__ wd3,
    __bf16* __restrict__ wqb, __bf16* __restrict__ wkb, __bf16* __restrict__ wvb,
    uchar* __restrict__ wcv8,
    __bf16* __restrict__ xpad, uchar* __restrict__ xpad8)
{
    const int bi = blockIdx.x;
    if (bi >= CC*CC/256) {
        // halo part: 64 blocks (16 per batch)
        const int sub = bi - CC*CC/256;
        const int b = sub >> 4;
        for (int t = (sub & 15)*256 + threadIdx.x; t < 516*32; t += 256*16) {
            const int icg = t & 31;
            const int p   = t >> 5;
            int xrow, xcol;
            if (p < 260)      { xrow = (p < 130) ? 0 : 129; xcol = p % 130; }
            else              { int q = p - 260; xrow = 1 + (q >> 1); xcol = (q & 1) ? 129 : 0; }
            const size_t off = (size_t)b*XPB + ((size_t)xrow*XR + xcol)*CC + icg*8;
            *(bf16x8*)&xpad[off] = (bf16x8){};
            *(unsigned long long*)&xpad8[off] = 0ull;
        }
        return;
    }
    int idx = bi * 256 + threadIdx.x;   // oc*256+ic
    const int oc = idx >> 8, ic = idx & 255;
    const int ocf32 = oc >> 5;
    const int gks = ic >> 4, khi = (ic >> 3) & 1;
    const int lane32 = khi*32 + (oc & 31);
    const int e = ic & 7;
    const size_t off32 = ((size_t)(gks*8 + ocf32)*64 + lane32)*8 + e;
    wqb[off32] = (__bf16)wq[idx];
    wkb[off32] = (__bf16)wk[idx];
    wvb[off32] = (__bf16)wv[idx];
    float w9[9];
    #pragma unroll
    for (int k=0;k<9;k++) w9[k] = wd3[(size_t)idx*9 + k];
    w9[4] += wd1[idx];
    #pragma unroll
    for (int t=0;t<9;t++) wcv8[(size_t)t*CC*CC + off32] = fp8b(w9[t] * 16.0f);
}

// ---------------- stage 128n x 256ic bf16 tile (one image row): xs[kq 0..31][n 0..131(132)][ic8]
__device__ __forceinline__ void stage_row128(const __bf16* __restrict__ xrb,
                                             __bf16* __restrict__ xs,
                                             int wid, int lane)
{
    #pragma unroll
    for (int j = 0; j < 16; ++j) {
        const int it = wid + 4*j;
        const int kq = it >> 1, ch = it & 1;
        gl_lds16(xrb + (size_t)(ch*64 + lane)*CC + kq*8, &xs[(size_t)(kq*132 + ch*64)*8]);
    }
}

// ---------------- 64oc x 128n x 256ic GEMM via 32x32x16 bf16; A packed (L2), B LDS
__device__ __forceinline__ void mfma_gemm32(const __bf16* __restrict__ wb,
                                            const __bf16* __restrict__ xs,
                                            int wid, int lane, int l31, int lhi,
                                            f32x16 acc[2][4])
{
    #pragma unroll
    for (int kb=0; kb<8; kb++) {
        bf16x8 af[4];
        #pragma unroll
        for (int f=0; f<2; f++)
            #pragma unroll
            for (int kk=0; kk<2; kk++)
                af[f*2+kk] = *(const bf16x8*)&wb[((size_t)((kb*2+kk)*8 + wid*2 + f)*64 + lane)*8];
        #pragma unroll
        for (int kk=0; kk<2; kk++)
            #pragma unroll
            for (int nf=0; nf<4; nf++) {
                bf16x8 br = *(const bf16x8*)&xs[(size_t)((kb*4 + kk*2 + lhi)*132 + nf*32 + l31)*8];
                #pragma unroll
                for (int f=0; f<2; f++)
                    acc[f][nf] = __builtin_amdgcn_mfma_f32_32x32x16_bf16(af[f*2+kk], br, acc[f][nf], 0, 0, 0);
            }
    }
}

// ---------------- FUSED: x(fp32,NCHW) -> LDS transpose -> xpad bf16+fp8 writes -> Q/K GEMMs
__global__ __launch_bounds__(256) void k_qk_mfma(const float* __restrict__ x,
    const __bf16* __restrict__ wqb, const float* __restrict__ bq,
    const __bf16* __restrict__ wkb, const float* __restrict__ bk,
    uchar* __restrict__ kp8, float* __restrict__ Qs,
    __bf16* __restrict__ xpad, uchar* __restrict__ xpad8)
{
    __shared__ __bf16 xs[32*132*8];
    __shared__ float Qpart[4][128];
    const int h  = blockIdx.x;
    const int n0 = h * 128;
    const int b  = blockIdx.y;
    const int tid = threadIdx.x;
    const int wid = tid >> 6, lane = tid & 63;
    const int l31 = lane & 31, lhi = lane >> 5;
    const int oc_base = wid*64;

    // phase 1: transpose-stage x fp32 -> xs bf16
    const float* xb = x + (size_t)b*CC*NN + (size_t)h*WW;
    {
        const int ic7 = tid & 7;
        const int col = ((tid >> 3) & 31) * 4;
        #pragma unroll
        for (int i = 0; i < 32; ++i) {
            const int ic = i*8 + ic7;
            float4 v = *(const float4*)&xb[(size_t)ic*NN + col];
            const int b0 = (i*132 + col)*8 + ic7;
            xs[b0]      = (__bf16)v.x;
            xs[b0 + 8]  = (__bf16)v.y;
            xs[b0 + 16] = (__bf16)v.z;
            xs[b0 + 24] = (__bf16)v.w;
        }
    }
    __syncthreads();

    // phase 1b: write global xpad bf16 + fp8 (512B-contiguous stores per col)
    {
        __bf16* xpb  = xpad  + (size_t)b*XPB + ((size_t)(h+1)*XR + 1)*CC;
        uchar*  xpb8 = xpad8 + (size_t)b*XPB + ((size_t)(h+1)*XR + 1)*CC;
        #pragma unroll
        for (int it = 0; it < 16; ++it) {
            const int o   = it*256 + tid;   // 4096 = 128 col x 32 kq
            const int col = o >> 5, kq = o & 31;
            bf16x8 v = *(const bf16x8*)&xs[(size_t)(kq*132 + col)*8];
            unsigned long long pk = 0;
            #pragma unroll
            for (int j = 0; j < 8; ++j)
                pk |= ((unsigned long long)fp8b((float)v[j])) << (8*j);
            *(bf16x8*)&xpb[(size_t)col*CC + kq*8] = v;
            *(unsigned long long*)&xpb8[(size_t)col*CC + kq*8] = pk;
        }
    }

    // --- Q phase ---
    f32x16 acc[2][4] = {};
    mfma_gemm32(wqb, xs, wid, lane, l31, lhi, acc);
    #pragma unroll
    for (int nf=0; nf<4; nf++) {
        float s = 0.0f;
        #pragma unroll
        for (int f=0; f<2; f++)
            #pragma unroll
            for (int reg=0; reg<16; reg++) {
                const int oc = oc_base + f*32 + (reg&3) + 8*(reg>>2) + 4*lhi;
                s += delu_f(acc[f][nf][reg] + bq[oc]);
            }
        s += __shfl_xor(s, 32);
        if (lhi == 0) Qpart[wid][nf*32 + l31] = s;
    }
    __syncthreads();
    if (tid < 128)
        Qs[(size_t)b*NN + n0 + tid] = Qpart[0][tid] + Qpart[1][tid] + Qpart[2][tid] + Qpart[3][tid];

    // --- K phase ---
    #pragma unroll
    for (int f=0; f<2; f++)
        #pragma unroll
        for (int nf=0; nf<4; nf++)
            acc[f][nf] = (f32x16){};
    mfma_gemm32(wkb, xs, wid, lane, l31, lhi, acc);
    #pragma unroll
    for (int f=0; f<2; f++) {
        #pragma unroll
        for (int reg=0; reg<16; reg++) {
            const int oc = oc_base + f*32 + (reg&3) + 8*(reg>>2) + 4*lhi;
            const float bias = bk[oc];
            uchar* kr = kp8 + ((size_t)b*CC + oc)*NN + n0;
            #pragma unroll
            for (int nf=0; nf<4; nf++)
                kr[nf*32 + l31] = fp8b(delu_f(acc[f][nf][reg] + bias));
        }
    }
}

// ---------------- Esum[b,c] = sum_n Qs[b,n] * k'[b,c,n]  (kp8 fp8 reads)
__global__ __launch_bounds__(256) void k_esum(const uchar* __restrict__ kp8,
    const float* __restrict__ Qs, float* __restrict__ Es)
{
    const int c = blockIdx.x & (CC-1), b = blockIdx.x >> 8;
    const int tid = threadIdx.x;
    const uchar* kr = kp8 + ((size_t)b*CC + c)*NN;
    const float4* qr = (const float4*)(Qs + (size_t)b*NN);
    float s = 0.0f;
    for (int i = tid; i < NN/8; i += 256) {
        unsigned long long kkb = *(const unsigned long long*)&kr[(size_t)i*8];
        float4 q0 = qr[2*i], q1 = qr[2*i+1];
        const float qv[8] = {q0.x,q0.y,q0.z,q0.w,q1.x,q1.y,q1.z,q1.w};
        #pragma unroll
        for (int j=0;j<8;j++)
            s = fmaf(fp8f((uchar)(kkb >> (8*j))), qv[j], s);
    }
    #pragma unroll
    for (int m=1; m<64; m<<=1) s += __shfl_xor(s, m, 64);
    __shared__ float red[4];
    if ((tid & 63) == 0) red[tid >> 6] = s;
    __syncthreads();
    if (tid == 0) Es[b*CC + c] = red[0] + red[1] + red[2] + red[3];
}

// ---------------- 3x3 conv (+folded 1x1) via 32x32x16 fp8 MFMA (R19-proven, depth-2 af), fp8 out
__global__ __launch_bounds__(256,2) void k_conv_mfma(const uchar* __restrict__ xpad8,
    const uchar* __restrict__ wcv8, const float* __restrict__ bd1,
    const float* __restrict__ bd3, uchar* __restrict__ convout8)
{
    __shared__ uchar xs8[2][6*132*16];
    // bijective XCD swizzle: nwg=512, 64 per XCD -> contiguous h-band per XCD
    const int orig = blockIdx.x;
    const int wg   = (orig & 7)*64 + (orig >> 3);
    const int b    = wg >> 7;
    const int h    = wg & 127;
    const int tid = threadIdx.x;
    const int wid = tid >> 6, lane = tid & 63;
    const int l31 = lane & 31, lhi = lane >> 5;
    const int oc_base = wid*64;
    const uchar* xpb8 = xpad8 + (size_t)b*XPB;

    f32x16 acc[2][4] = {};

    #define STAGE_CV8(bufsel, icb) do {                                         \
        const int ic0_ = (icb)*32;                                              \
        _Pragma("unroll")                                                       \
        for (int j = 0; j < 5; ++j) {                                           \
            const int w_ = wid + 4*j;                                           \
            if (w_ < 18) {                                                      \
                const int pair_ = w_ / 3, chunk_ = w_ % 3;                      \
                const int r_ = pair_ >> 1, g16_ = pair_ & 1;                    \
                const int col0_ = chunk_ * 64;                                  \
                if (col0_ + lane < XR)                                          \
                    gl_lds16(xpb8 + ((size_t)(h + r_)*XR + col0_ + lane)*CC + ic0_ + g16_*16, \
                             &xs8[bufsel][(size_t)(pair_*132 + col0_)*16]);     \
            }                                                                   \
        }                                                                       \
    } while (0)

    #define AF8_LOAD(dst, t, icb)                                               \
        _Pragma("unroll")                                                       \
        for (int f=0; f<2; f++)                                                 \
            _Pragma("unroll")                                                   \
            for (int kk=0; kk<2; kk++)                                          \
                dst[f*2+kk] = *(const long*)&wcv8[(size_t)(t)*CC*CC +           \
                    ((size_t)((((icb)*2 + kk)*8 + wid*2 + f))*64 + lane)*8];

    STAGE_CV8(0, 0);
    __syncthreads();

    #pragma unroll 1
    for (int icb = 0; icb < 8; ++icb) {
        long af8[2][4];
        AF8_LOAD(af8[0], 0, icb);
        if (icb < 7) STAGE_CV8((icb+1)&1, icb+1);
        #pragma unroll
        for (int t=0; t<9; ++t) {
            const int cur = t & 1, nxt = cur ^ 1;
            const int ky = t/3, kx = t%3;
            if (t < 8) { AF8_LOAD(af8[nxt], t+1, icb); }
            __builtin_amdgcn_s_setprio(1);
            #pragma unroll
            for (int kk=0; kk<2; kk++) {
                #pragma unroll
                for (int nf=0; nf<4; nf++) {
                    long br = *(const long*)&xs8[icb & 1][
                        (size_t)((ky*2 + kk)*132 + nf*32 + l31 + kx)*16 + lhi*8];
                    #pragma unroll
                    for (int f=0; f<2; f++)
                        acc[f][nf] = __builtin_amdgcn_mfma_f32_32x32x16_fp8_fp8(
                            af8[cur][f*2+kk], br, acc[f][nf], 0, 0, 0);
                }
            }
            __builtin_amdgcn_s_setprio(0);
        }
        __syncthreads();
    }
    #undef STAGE_CV8
    #undef AF8_LOAD

    #pragma unroll
    for (int f=0; f<2; f++) {
        #pragma unroll
        for (int reg=0; reg<16; reg++) {
            const int row = (reg & 3) + 8*(reg >> 2) + 4*lhi;
            const int oc = oc_base + f*32 + row;
            const float bias = bd1[oc] + bd3[oc];
            uchar* orow = convout8 + ((size_t)b*CC + oc)*NN + (size_t)h*WW;
            #pragma unroll
            for (int nf=0; nf<4; nf++) {
                const int w = nf*32 + l31;
                orow[w] = fp8b(acc[f][nf][reg]*0.0625f + bias);
            }
        }
    }
}

// ---------------- v projection via 32x32 MFMA + in-block denom + FINAL fused epilogue:
// out = x(from LDS xs, bf16) + g*(Es*k'*rn*(v+bv) + convout)
__global__ __launch_bounds__(256) void k_vattn_mfma(
    const __bf16* __restrict__ xpad,
    const __bf16* __restrict__ wvb, const float* __restrict__ bv,
    const uchar* __restrict__ kp8, const float* __restrict__ Es,
    const uchar* __restrict__ convout8,
    const float* __restrict__ gamma, float* __restrict__ out)
{
    __shared__ __bf16 xs[32*132*8];
    __shared__ float Dpart[4][128];
    __shared__ float rn_sh[128];
    const int h  = blockIdx.x;
    const int n0 = h * 128;
    const int b  = blockIdx.y;
    const int tid = threadIdx.x;
    const int wid = tid >> 6, lane = tid & 63;
    const int l31 = lane & 31, lhi = lane >> 5;
    const int oc_base = wid*64;
    const __bf16* xrb = xpad + (size_t)b*XPB + ((size_t)(h+1)*XR + 1)*CC;

    stage_row128(xrb, xs, wid, lane);
    __syncthreads();

    f32x16 acc[2][4] = {};
    mfma_gemm32(wvb, xs, wid, lane, l31, lhi, acc);

    // denom partials: sum over this wave's 64 oc of Es[oc]*k'[oc][n]
    float dpart[4] = {0.f,0.f,0.f,0.f};
    #pragma unroll
    for (int f=0; f<2; f++) {
        #pragma unroll
        for (int reg=0; reg<16; reg++) {
            const int oc = oc_base + f*32 + (reg&3) + 8*(reg>>2) + 4*lhi;
            const float e = Es[b*CC + oc];
            const uchar* kr = kp8 + ((size_t)b*CC + oc)*NN + n0;
            #pragma unroll
            for (int nf=0; nf<4; nf++)
                dpart[nf] = fmaf(e, fp8f(kr[nf*32 + l31]), dpart[nf]);
        }
    }
    #pragma unroll
    for (int nf=0; nf<4; nf++) {
        dpart[nf] += __shfl_xor(dpart[nf], 32);
        if (lhi == 0) Dpart[wid][nf*32 + l31] = dpart[nf];
    }
    __syncthreads();
    if (tid < 128)
        rn_sh[tid] = 1.0f / (Dpart[0][tid] + Dpart[1][tid] + Dpart[2][tid] + Dpart[3][tid] + EPSF);
    __syncthreads();

    const float g = gamma[0];
    #pragma unroll
    for (int f=0; f<2; f++) {
        #pragma unroll
        for (int reg=0; reg<16; reg++) {
            const int oc = oc_base + f*32 + (reg&3) + 8*(reg>>2) + 4*lhi;
            const float eg = Es[b*CC + oc] * g;
            const float bias = bv[oc];
            const uchar* kr = kp8 + ((size_t)b*CC + oc)*NN + n0;
            const uchar* cr = convout8 + ((size_t)b*CC + oc)*NN + n0;
            const __bf16* xr = &xs[(size_t)((oc >> 3)*132)*8 + (oc & 7)];
            float* orow = out + ((size_t)b*CC + oc)*NN + n0;
            #pragma unroll
            for (int nf=0; nf<4; nf++) {
                const int w = nf*32 + l31;
                const float attn = eg*fp8f(kr[w])*rn_sh[w]*(acc[f][nf][reg] + bias);
                const float xv = (float)xr[(size_t)w*8];
                orow[w] = xv + attn + g*fp8f(cr[w]);
            }
        }
    }
}

extern "C" void kernel_launch(void* const* d_in, const int* in_sizes, int n_in,
                              void* d_out, int out_size, void* d_ws, size_t ws_size,
                              hipStream_t stream)
{
    const float* x     = (const float*)d_in[0];
    const float* wq    = (const float*)d_in[1];
    const float* bq    = (const float*)d_in[2];
    const float* wk    = (const float*)d_in[3];
    const float* bk    = (const float*)d_in[4];
    const float* wv    = (const float*)d_in[5];
    const float* bv    = (const float*)d_in[6];
    const float* wd1   = (const float*)d_in[7];
    const float* bd1   = (const float*)d_in[8];
    const float* wd3   = (const float*)d_in[9];
    const float* bd3   = (const float*)d_in[10];
    const float* gamma = (const float*)d_in[11];
    float* out = (float*)d_out;

    uchar*  kp8    = (uchar*)d_ws;                      // B*C*N bytes (16.8 MB)
    uchar*  cvout8 = kp8 + (size_t)BB*CC*NN;            // B*C*N bytes (16.8 MB)
    float*  Qs     = (float*)(cvout8 + (size_t)BB*CC*NN); // B*N
    float*  Es     = Qs + (size_t)BB*NN;                // B*C
    uchar*  wcv8   = (uchar*)(Es + (size_t)BB*CC);      // [9][256][256] fp8 (0.6 MB)
    __bf16* wqb    = (__bf16*)(wcv8 + (size_t)9*CC*CC); // [256][256] bf16, 32x32-pack
    __bf16* wkb    = wqb + (size_t)CC*CC;
    __bf16* wvb    = wkb + (size_t)CC*CC;
    __bf16* xpad   = wvb + (size_t)CC*CC;               // [4][130][130][256] bf16 (34.6 MB)
    uchar*  xpad8  = (uchar*)(xpad + (size_t)BB*XPB);   // [4][130][130][256] fp8 (17.3 MB)

    k_prep_halo <<<dim3(CC*CC/256 + 16*BB), 256, 0, stream>>>(
                    wq, wk, wv, wd1, wd3, wqb, wkb, wvb, wcv8, xpad, xpad8);
    k_qk_mfma   <<<dim3(HH, BB), 256, 0, stream>>>(x, wqb, bq, wkb, bk, kp8, Qs, xpad, xpad8);
    k_esum      <<<dim3(BB*CC), 256, 0, stream>>>(kp8, Qs, Es);
    k_conv_mfma <<<dim3(HH*BB), 256, 0, stream>>>(xpad8, wcv8, bd1, bd3, cvout8);
    k_vattn_mfma<<<dim3(HH, BB), 256, 0, stream>>>(xpad, wvb, bv, kp8, Es, cvout8, gamma, out);
}